// Round 7
// baseline (858.650 us; speedup 1.0000x reference)
//
#include <hip/hip_runtime.h>
#include <hip/hip_fp16.h>

// Instant-NGP style hash-grid encoder, level-partitioned + spatially bucketed.
// N=1048576 points, 16 levels, LEVEL_DIM=2, HASHMAP_SIZE=2^19, BASE_RES=16.
//
// Hash identity: idx = ((cx*P0 + cy*P1 + cz*P2) & (2^19-1)) ^ lvl, in uint32
// (low 19 bits exact under 32-bit wraparound; corners >= 0; lvl < 16).
//
// R7: the kernel is L2-gather-request bound (R2..R6: FETCH 425->283 MB at
// constant 620us; 11.2 req/cyc/XCD). Reduce REQUEST COUNT via spatial
// bucketing: points are binned into a 32^3 grid; one 64-thread block
// processes one (bucket, level). Within a wave, bucketed points share cube
// corners at low levels -> wave coalescing/broadcast collapses 8 gathers
// onto few lines (L0-L2 ~free, L3 ~2x, L4 ~1.1x, L5-15 irreducible).
// Savings concentrate in light levels, so levels are fractionally assigned
// to XCDs by COMPUTED request-count weights (tables may be replicated in
// two XCDs' L2s; only one level per XCD at a time matters). R3's Sched
// machinery, now with measured-model weights + margin on light levels.
//
// Pipeline: memset(hist) -> hist -> scan(offsets,work) -> scatter(xs,perm)
//           -> hash_bucket (ws f16, level-major) -> transpose_scatter (out).
// Per-point arithmetic identical to reference modulo f16 ws rounding
// (|v|<=1e-4 -> +3e-8 abs err vs 2e-6 threshold).

#define NUM_LEVELS 16
#define HASHMAP_SIZE (1u << 19)
#define HASH_MASK (HASHMAP_SIZE - 1u)
#define BASE_RES 16
#define NXCD 8
#define NBX 32
#define NBUCKETS (NBX * NBX * NBX)
#define MAX_SEG 8

struct Sched {
  int j_end[NXCD][MAX_SEG];
  int lvl[NXCD][MAX_SEG];
  int c0[NXCD][MAX_SEG];
  int nseg[NXCD];
  int J;
};

__device__ __forceinline__ int bucket_of(float px, float py, float pz) {
  const float UB = (float)(1.0 - 1e-6);
  const float xn0 = fminf(fmaxf((px + 1.0f) * 0.5f, 0.0f), UB);
  const float xn1 = fminf(fmaxf((py + 1.0f) * 0.5f, 0.0f), UB);
  const float xn2 = fminf(fmaxf((pz + 1.0f) * 0.5f, 0.0f), UB);
  const int bx = (int)(xn0 * (float)NBX);  // xn < 1 -> bx <= 31
  const int by = (int)(xn1 * (float)NBX);
  const int bz = (int)(xn2 * (float)NBX);
  return (bx << 10) | (by << 5) | bz;
}

__global__ __launch_bounds__(256) void hist_kernel(
    const float* __restrict__ x, unsigned* __restrict__ hist, int n) {
  for (int i = blockIdx.x * blockDim.x + threadIdx.x; i < n;
       i += gridDim.x * blockDim.x) {
    const float px = __builtin_nontemporal_load(x + 3 * (size_t)i + 0);
    const float py = __builtin_nontemporal_load(x + 3 * (size_t)i + 1);
    const float pz = __builtin_nontemporal_load(x + 3 * (size_t)i + 2);
    atomicAdd(&hist[bucket_of(px, py, pz)], 1u);
  }
}

// one block, 1024 threads: exclusive scan of hist[NBUCKETS] -> offsets, work
__global__ __launch_bounds__(1024) void scan_kernel(
    const unsigned* __restrict__ hist, unsigned* __restrict__ offsets,
    unsigned* __restrict__ work, int n) {
  __shared__ unsigned part[1024];
  const int t = threadIdx.x;
  const int per = NBUCKETS / 1024;  // 32
  unsigned vals[32];
  unsigned sum = 0;
#pragma unroll
  for (int k = 0; k < per; ++k) {
    vals[k] = hist[t * per + k];
    sum += vals[k];
  }
  part[t] = sum;
  __syncthreads();
  for (int ofs = 1; ofs < 1024; ofs <<= 1) {
    const unsigned v = (t >= ofs) ? part[t - ofs] : 0u;
    __syncthreads();
    part[t] += v;
    __syncthreads();
  }
  unsigned excl = (t == 0) ? 0u : part[t - 1];
#pragma unroll
  for (int k = 0; k < per; ++k) {
    offsets[t * per + k] = excl;
    work[t * per + k] = excl;
    excl += vals[k];
  }
  if (t == 1023) offsets[NBUCKETS] = excl;  // == n
}

__global__ __launch_bounds__(256) void scatter_kernel(
    const float* __restrict__ x, unsigned* __restrict__ work,
    float* __restrict__ xs, int* __restrict__ perm, int n) {
  for (int i = blockIdx.x * blockDim.x + threadIdx.x; i < n;
       i += gridDim.x * blockDim.x) {
    const float px = __builtin_nontemporal_load(x + 3 * (size_t)i + 0);
    const float py = __builtin_nontemporal_load(x + 3 * (size_t)i + 1);
    const float pz = __builtin_nontemporal_load(x + 3 * (size_t)i + 2);
    const int b = bucket_of(px, py, pz);
    const unsigned p = atomicAdd(&work[b], 1u);
    xs[3 * (size_t)p + 0] = px;  // plain stores: main kernel reads soon (L2)
    xs[3 * (size_t)p + 1] = py;
    xs[3 * (size_t)p + 2] = pz;
    perm[p] = i;
  }
}

__global__ __launch_bounds__(64) void hash_bucket_kernel(
    const float* __restrict__ xs,      // [N,3] bucket-ordered
    const float* __restrict__ tables,  // [16, 2^19, 2]
    const unsigned* __restrict__ offsets,
    unsigned* __restrict__ ws,         // [16, N] of __half2
    int n, Sched s) {
  const int xcd = blockIdx.x % NXCD;  // HW round-robin wg->XCD
  const int j = blockIdx.x / NXCD;

  int lvl = -1, bucket = 0, beg = 0;
  const int ns = s.nseg[xcd];
  for (int k = 0; k < ns; ++k) {
    const int end = s.j_end[xcd][k];
    if (j >= beg && j < end) {
      lvl = s.lvl[xcd][k];
      bucket = s.c0[xcd][k] + (j - beg);
    }
    beg = end;
  }
  if (lvl < 0) return;  // padding block

  const unsigned start = offsets[bucket];
  const unsigned stop = offsets[bucket + 1];

  const unsigned P0 = 1546061u, P1 = 1005013u, P2 = 1673733u;
  const float UB = (float)(1.0 - 1e-6);
  const float res = (float)(BASE_RES << lvl);
  const float2* __restrict__ tbl =
      (const float2*)(tables + (size_t)lvl * HASHMAP_SIZE * 2);

  for (unsigned p = start + threadIdx.x; p < stop; p += 64) {
    const float px = __builtin_nontemporal_load(xs + 3 * (size_t)p + 0);
    const float py = __builtin_nontemporal_load(xs + 3 * (size_t)p + 1);
    const float pz = __builtin_nontemporal_load(xs + 3 * (size_t)p + 2);

    const float xn0 = fminf(fmaxf((px + 1.0f) * 0.5f, 0.0f), UB);
    const float xn1 = fminf(fmaxf((py + 1.0f) * 0.5f, 0.0f), UB);
    const float xn2 = fminf(fmaxf((pz + 1.0f) * 0.5f, 0.0f), UB);

    const float s0 = xn0 * res, s1 = xn1 * res, s2 = xn2 * res;
    const float f0 = floorf(s0), f1 = floorf(s1), f2 = floorf(s2);
    const float fr0 = s0 - f0, fr1 = s1 - f1, fr2 = s2 - f2;
    const unsigned c0 = (unsigned)f0, c1 = (unsigned)f1, c2 = (unsigned)f2;

    const unsigned base = c0 * P0 + c1 * P1 + c2 * P2;  // uint32 wrap OK
    const float g0 = 1.0f - fr0, g1 = 1.0f - fr1, g2 = 1.0f - fr2;

    float acc0 = 0.0f, acc1 = 0.0f;
#pragma unroll
    for (int corner = 0; corner < 8; ++corner) {
      unsigned h = base;
      float w = 1.0f;
      if (corner & 4) { h += P0; w *= fr0; } else { w *= g0; }
      if (corner & 2) { h += P1; w *= fr1; } else { w *= g1; }
      if (corner & 1) { h += P2; w *= fr2; } else { w *= g2; }
      h = (h & HASH_MASK) ^ (unsigned)lvl;
      const float2 e = tbl[h];  // normal load: keep table hot in L2
      acc0 += e.x * w;
      acc1 += e.y * w;
    }

    const __half2 h2 = __floats2half2_rn(acc0, acc1);
    __builtin_nontemporal_store(*(const unsigned*)&h2,
                                ws + (size_t)lvl * n + p);
  }
}

__global__ __launch_bounds__(256) void transpose_scatter_kernel(
    const unsigned* __restrict__ ws,  // [16, N] of __half2, bucket order
    const int* __restrict__ perm,     // bucket pos -> original index
    float* __restrict__ out,          // [N, 32] original order
    int n) {
  const int p = blockIdx.x * blockDim.x + threadIdx.x;
  if (p >= n) return;

  float outv[2 * NUM_LEVELS];
#pragma unroll
  for (int lvl = 0; lvl < NUM_LEVELS; ++lvl) {
    const unsigned u = __builtin_nontemporal_load(ws + (size_t)lvl * n + p);
    const __half2 h2 = *(const __half2*)&u;
    const float2 f = __half22float2(h2);
    outv[2 * lvl + 0] = f.x;
    outv[2 * lvl + 1] = f.y;
  }
  const int orig = perm[p];
  // plain full-row stores (R5 lesson: NT stores on dense output ~10x slower)
  float4* o = (float4*)(out + (size_t)orig * (2 * NUM_LEVELS));
#pragma unroll
  for (int k = 0; k < 8; ++k) o[k] = ((const float4*)outv)[k];
}

// ---------- fallback path (R6): no bucketing ----------
__global__ __launch_bounds__(256) void hash_level_kernel(
    const float* __restrict__ x, const float* __restrict__ tables,
    unsigned* __restrict__ ws, int n, int nchunk) {
  const int b = blockIdx.x;
  const int lvl_lo = b % NXCD;
  const int r = b / NXCD;
  const int chunk = r % nchunk;
  const int lvl = lvl_lo + NXCD * (r / nchunk);
  const int i = chunk * 256 + (int)threadIdx.x;
  if (i >= n) return;

  const unsigned P0 = 1546061u, P1 = 1005013u, P2 = 1673733u;
  const float UB = (float)(1.0 - 1e-6);
  const float px = __builtin_nontemporal_load(x + 3 * (size_t)i + 0);
  const float py = __builtin_nontemporal_load(x + 3 * (size_t)i + 1);
  const float pz = __builtin_nontemporal_load(x + 3 * (size_t)i + 2);
  const float xn0 = fminf(fmaxf((px + 1.0f) * 0.5f, 0.0f), UB);
  const float xn1 = fminf(fmaxf((py + 1.0f) * 0.5f, 0.0f), UB);
  const float xn2 = fminf(fmaxf((pz + 1.0f) * 0.5f, 0.0f), UB);
  const float res = (float)(BASE_RES << lvl);
  const float s0 = xn0 * res, s1 = xn1 * res, s2 = xn2 * res;
  const float f0 = floorf(s0), f1 = floorf(s1), f2 = floorf(s2);
  const float fr0 = s0 - f0, fr1 = s1 - f1, fr2 = s2 - f2;
  const unsigned base =
      (unsigned)f0 * P0 + (unsigned)f1 * P1 + (unsigned)f2 * P2;
  const float2* __restrict__ tbl =
      (const float2*)(tables + (size_t)lvl * HASHMAP_SIZE * 2);
  const float g0 = 1.0f - fr0, g1 = 1.0f - fr1, g2 = 1.0f - fr2;
  float acc0 = 0.0f, acc1 = 0.0f;
#pragma unroll
  for (int corner = 0; corner < 8; ++corner) {
    unsigned h = base;
    float w = 1.0f;
    if (corner & 4) { h += P0; w *= fr0; } else { w *= g0; }
    if (corner & 2) { h += P1; w *= fr1; } else { w *= g1; }
    if (corner & 1) { h += P2; w *= fr2; } else { w *= g2; }
    h = (h & HASH_MASK) ^ (unsigned)lvl;
    const float2 e = tbl[h];
    acc0 += e.x * w;
    acc1 += e.y * w;
  }
  const __half2 h2 = __floats2half2_rn(acc0, acc1);
  __builtin_nontemporal_store(*(const unsigned*)&h2, ws + (size_t)lvl * n + i);
}

__global__ __launch_bounds__(256) void transpose_kernel(
    const unsigned* __restrict__ ws, float* __restrict__ out, int n) {
  const int i = blockIdx.x * blockDim.x + threadIdx.x;
  if (i >= n) return;
  float outv[2 * NUM_LEVELS];
#pragma unroll
  for (int lvl = 0; lvl < NUM_LEVELS; ++lvl) {
    const unsigned u = __builtin_nontemporal_load(ws + (size_t)lvl * n + i);
    const __half2 h2 = *(const __half2*)&u;
    const float2 f = __half22float2(h2);
    outv[2 * lvl + 0] = f.x;
    outv[2 * lvl + 1] = f.y;
  }
  float4* o = (float4*)(out + (size_t)i * (2 * NUM_LEVELS));
#pragma unroll
  for (int k = 0; k < 8; ++k) o[k] = ((const float4*)outv)[k];
}

// ---------- host ----------
static void build_sched(Sched* s, int nchunk) {
  // post-bucketing request-count weights (light levels padded with margin)
  const double c[NUM_LEVELS] = {0.15, 0.18, 0.30, 0.65, 0.95, 1, 1, 1,
                                1,    1,    1,    1,    1,    1, 1, 1};
  double total = 0;
  for (int l = 0; l < NUM_LEVELS; ++l) total += c[l] * nchunk;
  const double target = total / NXCD;

  for (int xx = 0; xx < NXCD; ++xx) s->nseg[xx] = 0;
  int xcd = 0;
  double acc = 0;
  for (int l = 0; l < NUM_LEVELS; ++l) {
    int cpos = 0;
    while (cpos < nchunk) {
      int take;
      if (xcd >= NXCD - 1) {
        take = nchunk - cpos;
      } else {
        const double room = target - acc;
        take = (int)(room / c[l] + 0.999999);
        if (take > nchunk - cpos) take = nchunk - cpos;
        if (take <= 0) { ++xcd; acc = 0; continue; }
      }
      int k = s->nseg[xcd];
      if (k >= MAX_SEG) k = MAX_SEG - 1;
      const int beg = (k == 0) ? 0 : s->j_end[xcd][k - 1];
      s->j_end[xcd][k] = beg + take;
      s->lvl[xcd][k] = l;
      s->c0[xcd][k] = cpos;
      s->nseg[xcd] = k + 1;
      cpos += take;
      acc += (double)take * c[l];
      if (xcd < NXCD - 1 && acc >= target - 1e-6) { ++xcd; acc = 0; }
    }
  }
  int J = 0;
  for (int xx = 0; xx < NXCD; ++xx) {
    const int k = s->nseg[xx];
    const int e = k ? s->j_end[xx][k - 1] : 0;
    if (e > J) J = e;
  }
  s->J = J;
}

extern "C" void kernel_launch(void* const* d_in, const int* in_sizes, int n_in,
                              void* d_out, int out_size, void* d_ws, size_t ws_size,
                              hipStream_t stream) {
  const float* x = (const float*)d_in[0];
  const float* tables = (const float*)d_in[1];
  float* out = (float*)d_out;
  const int n = in_sizes[0] / 3;

  // workspace layout (256B aligned)
  size_t off = 0;
  auto alloc = [&](size_t bytes) {
    size_t r = off;
    off = (off + bytes + 255) & ~(size_t)255;
    return r;
  };
  const size_t ws_f16_off = alloc((size_t)NUM_LEVELS * n * 4);
  const size_t xs_off = alloc((size_t)n * 3 * 4);
  const size_t perm_off = alloc((size_t)n * 4);
  const size_t offsets_off = alloc((size_t)(NBUCKETS + 1) * 4);
  const size_t work_off = alloc((size_t)NBUCKETS * 4);
  const size_t hist_off = alloc((size_t)NBUCKETS * 4);
  const size_t need_bucket = off;
  const size_t need_plain = (size_t)NUM_LEVELS * n * 4;

  char* wsb = (char*)d_ws;

  if (ws_size >= need_bucket) {
    unsigned* wsh = (unsigned*)(wsb + ws_f16_off);
    float* xs = (float*)(wsb + xs_off);
    int* perm = (int*)(wsb + perm_off);
    unsigned* offsets = (unsigned*)(wsb + offsets_off);
    unsigned* work = (unsigned*)(wsb + work_off);
    unsigned* hist = (unsigned*)(wsb + hist_off);

    hipMemsetAsync(hist, 0, (size_t)NBUCKETS * 4, stream);
    hist_kernel<<<2048, 256, 0, stream>>>(x, hist, n);
    scan_kernel<<<1, 1024, 0, stream>>>(hist, offsets, work, n);
    scatter_kernel<<<2048, 256, 0, stream>>>(x, work, xs, perm, n);

    Sched s;
    build_sched(&s, NBUCKETS);
    hash_bucket_kernel<<<NXCD * s.J, 64, 0, stream>>>(xs, tables, offsets,
                                                      wsh, n, s);
    const int nchunk_t = (n + 255) / 256;
    transpose_scatter_kernel<<<nchunk_t, 256, 0, stream>>>(wsh, perm, out, n);
  } else if (ws_size >= need_plain) {
    unsigned* wsh = (unsigned*)wsb;
    const int nchunk = (n + 255) / 256;
    hash_level_kernel<<<nchunk * NUM_LEVELS, 256, 0, stream>>>(x, tables, wsh,
                                                               n, nchunk);
    transpose_kernel<<<nchunk, 256, 0, stream>>>(wsh, out, n);
  }
}

// Round 8
// 654.334 us; speedup vs baseline: 1.3122x; 1.3122x over previous
//
#include <hip/hip_runtime.h>
#include <hip/hip_fp16.h>

// Instant-NGP style hash-grid encoder, level-partitioned for L2 locality.
// N=1048576 points, 16 levels, LEVEL_DIM=2, HASHMAP_SIZE=2^19, BASE_RES=16.
//
// Hash identity: idx = ((cx*P0 + cy*P1 + cz*P2) & (2^19-1)) ^ lvl, in uint32
// (low 19 bits exact under 32-bit wraparound; corners >= 0; lvl < 16).
//
// R8 = best-known config (R5 main + R6 transpose), after R7's bucketing
// experiment regressed (hash scatters each level's live entries across the
// full 2^19 slot space -> line footprint ~4MB for all levels >= 2; wave
// same-line merging only helps L0-L2 ~ 15% of requests; presort cost > win).
//
// Structure:
//  - balanced level->XCD: XCD k gets levels k and k+8 (HW round-robin on
//    blockIdx%8), time-partitioned (level k+8 dispatches strictly after k),
//    so each XCD's 4 MiB L2 hosts exactly ONE 4 MiB table at a time
//  - f16 level-major intermediate ws[16][N] (__half2; |v|<=1e-4 -> f16 adds
//    <=3e-8 abs error vs 2e-6 threshold) -> halves ws traffic
//  - NT loads for streaming x / ws reads; NT stores ONLY for ws (R5 lesson:
//    NT stores on the dense f32 output were ~10x slower -> plain stores)
//  - table gathers stay NORMAL loads (16x L2 reuse is the whole point)
//
// Evidence this is the roofline: FETCH 425->283 MB across R2..R6 at constant
// ~620us (not HBM-bound); PPT=2 neutral (not latency-bound); 134M random
// line-requests / 8 XCDs / 620us = 11.2 req/cyc/XCD ~= 70% of L2 service,
// the balls-in-bins efficiency for random addressing.

#define NUM_LEVELS 16
#define HASHMAP_SIZE (1u << 19)
#define HASH_MASK (HASHMAP_SIZE - 1u)
#define BASE_RES 16
#define NXCD 8

__global__ __launch_bounds__(256) void hash_level_kernel(
    const float* __restrict__ x,       // [N,3]
    const float* __restrict__ tables,  // [16, 2^19, 2]
    unsigned* __restrict__ ws,         // [16, N] of __half2
    int n, int nchunk) {
  // XCD k <- levels k and k+8 (HW round-robin wg->XCD on b%8); level k+8's
  // blocks dispatch strictly after all of level k's.
  const int b = blockIdx.x;
  const int lvl_lo = b % NXCD;
  const int r = b / NXCD;
  const int chunk = r % nchunk;
  const int lvl = lvl_lo + NXCD * (r / nchunk);

  const int i = chunk * 256 + (int)threadIdx.x;
  if (i >= n) return;

  const unsigned P0 = 1546061u, P1 = 1005013u, P2 = 1673733u;
  const float UB = (float)(1.0 - 1e-6);

  const float px = __builtin_nontemporal_load(x + 3 * (size_t)i + 0);
  const float py = __builtin_nontemporal_load(x + 3 * (size_t)i + 1);
  const float pz = __builtin_nontemporal_load(x + 3 * (size_t)i + 2);

  const float xn0 = fminf(fmaxf((px + 1.0f) * 0.5f, 0.0f), UB);
  const float xn1 = fminf(fmaxf((py + 1.0f) * 0.5f, 0.0f), UB);
  const float xn2 = fminf(fmaxf((pz + 1.0f) * 0.5f, 0.0f), UB);

  const float res = (float)(BASE_RES << lvl);
  const float s0 = xn0 * res, s1 = xn1 * res, s2 = xn2 * res;
  const float f0 = floorf(s0), f1 = floorf(s1), f2 = floorf(s2);
  const float fr0 = s0 - f0, fr1 = s1 - f1, fr2 = s2 - f2;
  const unsigned c0 = (unsigned)f0, c1 = (unsigned)f1, c2 = (unsigned)f2;

  const unsigned base = c0 * P0 + c1 * P1 + c2 * P2;  // uint32 wrap OK
  const float2* __restrict__ tbl =
      (const float2*)(tables + (size_t)lvl * HASHMAP_SIZE * 2);
  const float g0 = 1.0f - fr0, g1 = 1.0f - fr1, g2 = 1.0f - fr2;

  float acc0 = 0.0f, acc1 = 0.0f;
#pragma unroll
  for (int corner = 0; corner < 8; ++corner) {
    unsigned h = base;
    float w = 1.0f;
    if (corner & 4) { h += P0; w *= fr0; } else { w *= g0; }
    if (corner & 2) { h += P1; w *= fr1; } else { w *= g1; }
    if (corner & 1) { h += P2; w *= fr2; } else { w *= g2; }
    h = (h & HASH_MASK) ^ (unsigned)lvl;
    const float2 e = tbl[h];  // normal load: keep table hot in L2
    acc0 += e.x * w;
    acc1 += e.y * w;
  }

  // f16 pack (|acc| <= 1e-4 -> abs err <= 3e-8), coalesced streaming store
  const __half2 h2 = __floats2half2_rn(acc0, acc1);
  __builtin_nontemporal_store(*(const unsigned*)&h2, ws + (size_t)lvl * n + i);
}

__global__ __launch_bounds__(256) void transpose_kernel(
    const unsigned* __restrict__ ws,  // [16, N] of __half2
    float* __restrict__ out,          // [N, 32]
    int n) {
  const int i = blockIdx.x * blockDim.x + threadIdx.x;
  if (i >= n) return;

  float outv[2 * NUM_LEVELS];
#pragma unroll
  for (int lvl = 0; lvl < NUM_LEVELS; ++lvl) {
    const unsigned u = __builtin_nontemporal_load(ws + (size_t)lvl * n + i);
    const __half2 h2 = *(const __half2*)&u;
    const float2 f = __half22float2(h2);
    outv[2 * lvl + 0] = f.x;
    outv[2 * lvl + 1] = f.y;
  }
  // plain stores (R5 lesson: NT stores on dense output ~10x slower)
  float4* o = (float4*)(out + (size_t)i * (2 * NUM_LEVELS));
#pragma unroll
  for (int k = 0; k < 8; ++k) o[k] = ((const float4*)outv)[k];
}

// fallback: direct f32 writes to out[N,32] (if ws too small; same decode)
__global__ __launch_bounds__(256) void hash_direct_kernel(
    const float* __restrict__ x, const float* __restrict__ tables,
    float* __restrict__ out, int n, int nchunk) {
  const int b = blockIdx.x;
  const int lvl_lo = b % NXCD;
  const int r = b / NXCD;
  const int chunk = r % nchunk;
  const int lvl = lvl_lo + NXCD * (r / nchunk);
  const int i = chunk * 256 + (int)threadIdx.x;
  if (i >= n) return;

  const unsigned P0 = 1546061u, P1 = 1005013u, P2 = 1673733u;
  const float UB = (float)(1.0 - 1e-6);
  const float px = x[3 * (size_t)i + 0];
  const float py = x[3 * (size_t)i + 1];
  const float pz = x[3 * (size_t)i + 2];
  const float xn0 = fminf(fmaxf((px + 1.0f) * 0.5f, 0.0f), UB);
  const float xn1 = fminf(fmaxf((py + 1.0f) * 0.5f, 0.0f), UB);
  const float xn2 = fminf(fmaxf((pz + 1.0f) * 0.5f, 0.0f), UB);
  const float res = (float)(BASE_RES << lvl);
  const float s0 = xn0 * res, s1 = xn1 * res, s2 = xn2 * res;
  const float f0 = floorf(s0), f1 = floorf(s1), f2 = floorf(s2);
  const float fr0 = s0 - f0, fr1 = s1 - f1, fr2 = s2 - f2;
  const unsigned base =
      (unsigned)f0 * P0 + (unsigned)f1 * P1 + (unsigned)f2 * P2;
  const float2* __restrict__ tbl =
      (const float2*)(tables + (size_t)lvl * HASHMAP_SIZE * 2);
  const float g0 = 1.0f - fr0, g1 = 1.0f - fr1, g2 = 1.0f - fr2;
  float acc0 = 0.0f, acc1 = 0.0f;
#pragma unroll
  for (int corner = 0; corner < 8; ++corner) {
    unsigned h = base;
    float w = 1.0f;
    if (corner & 4) { h += P0; w *= fr0; } else { w *= g0; }
    if (corner & 2) { h += P1; w *= fr1; } else { w *= g1; }
    if (corner & 1) { h += P2; w *= fr2; } else { w *= g2; }
    h = (h & HASH_MASK) ^ (unsigned)lvl;
    const float2 e = tbl[h];
    acc0 += e.x * w;
    acc1 += e.y * w;
  }
  float2* o = (float2*)(out + (size_t)i * (2 * NUM_LEVELS) + 2 * lvl);
  *o = make_float2(acc0, acc1);
}

extern "C" void kernel_launch(void* const* d_in, const int* in_sizes, int n_in,
                              void* d_out, int out_size, void* d_ws, size_t ws_size,
                              hipStream_t stream) {
  const float* x = (const float*)d_in[0];
  const float* tables = (const float*)d_in[1];
  float* out = (float*)d_out;
  const int n = in_sizes[0] / 3;  // N points

  const int block = 256;
  const int nchunk = (n + block - 1) / block;
  const int nblocks = nchunk * NUM_LEVELS;

  const size_t ws_needed = (size_t)NUM_LEVELS * n * sizeof(unsigned);
  if (ws_size >= ws_needed) {
    unsigned* ws = (unsigned*)d_ws;
    hash_level_kernel<<<nblocks, block, 0, stream>>>(x, tables, ws, n, nchunk);
    transpose_kernel<<<nchunk, block, 0, stream>>>(ws, out, n);
  } else {
    hash_direct_kernel<<<nblocks, block, 0, stream>>>(x, tables, out, n, nchunk);
  }
}